// Round 11
// baseline (218.994 us; speedup 1.0000x reference)
//
#include <hip/hip_runtime.h>
#include <math.h>

#define TPB 256

constexpr int Dd = 256;
constexpr int Nn = 1024;
constexpr int Mm = 1025;      // Nn + 1 (with dustbin)
constexpr int LDKc = 1040;    // padded row stride for K / KT (16-float aligned)
constexpr int SINK_ITERS = 100;
constexpr int NB  = 64;       // flow blocks
constexpr int PT  = 1024;     // threads per flow block (16 waves, 1 wave = 1 row)

// ---- workspace layout (float offsets) ----
constexpr size_t OF_MD0   = 0;
constexpr size_t OF_MD1   = OF_MD0  + (size_t)Dd*Nn;
constexpr size_t OF_MD0T  = OF_MD1  + (size_t)Dd*Nn;
constexpr size_t OF_MD1T  = OF_MD0T + (size_t)Dd*Nn;
constexpr size_t OF_HA    = OF_MD1T + (size_t)Dd*Nn;
constexpr size_t OF_HBT   = OF_HA   + (size_t)Nn*64;
constexpr size_t OF_WZ1T  = OF_HBT  + (size_t)Nn*64;
constexpr size_t OF_WZ2T  = OF_WZ1T + (size_t)Dd*Dd;
constexpr size_t OF_ZA    = OF_WZ2T + (size_t)64*Dd;   // zAr (sentinel-ready, reset -1e30)
constexpr size_t OF_ZB    = OF_ZA   + Nn;              // zBr
constexpr size_t OF_ROWM  = OF_ZB   + Nn;
constexpr size_t OF_ROWS  = OF_ROWM + Nn;
constexpr size_t OF_CMP   = OF_ROWS + Nn;        // 16 x 1024 column partial max
constexpr size_t OF_CSP   = OF_CMP  + (size_t)16*Nn;
constexpr size_t OF_AV    = OF_CSP  + (size_t)16*Nn;  // a vector (sign-parity; reset 0)
constexpr size_t OF_BV    = OF_AV   + LDKc;           // b vector (sign-parity; reset 0)
constexpr size_t OF_RINV  = OF_BV   + LDKc;           // 1/rowsum; reset -1, ready >= 0
constexpr size_t OF_IDX0  = OF_RINV + LDKc;           // int; reset -1, ready >= 0
constexpr size_t OF_MAX0  = OF_IDX0 + Nn;             // reset -1, ready >= 0
constexpr size_t OF_IDX1  = OF_MAX0 + Nn;             // int; reset -1
constexpr size_t OF_ATTN  = OF_IDX1 + Nn;
constexpr size_t OF_PART  = OF_ATTN + (size_t)Nn*Nn;  // zfeat partials (4 x 256K floats)
// K/KT placement: path A aliases attn+part (buildK runs late); path B is a separate
// region after part (buildK overlaps k_h). Chosen at runtime from ws_size.
constexpr size_t OF_K_A   = OF_ATTN;
constexpr size_t OF_K_B   = OF_PART + (size_t)4*Nn*Dd;
constexpr size_t NEED_B_FLOATS = OF_K_B + (size_t)2*Mm*LDKc;

// ---------- agent-scope (coherence-point) access helpers ----------
__device__ __forceinline__ float aloadf(const float* p) {
  return __hip_atomic_load((float*)p, __ATOMIC_RELAXED, __HIP_MEMORY_SCOPE_AGENT);
}
__device__ __forceinline__ int aloadi(const int* p) {
  return __hip_atomic_load((int*)p, __ATOMIC_RELAXED, __HIP_MEMORY_SCOPE_AGENT);
}
__device__ __forceinline__ void astoref(float* p, float v) {
  __hip_atomic_store(p, v, __ATOMIC_RELAXED, __HIP_MEMORY_SCOPE_AGENT);
}
__device__ __forceinline__ void astorei(int* p, int v) {
  __hip_atomic_store(p, v, __ATOMIC_RELAXED, __HIP_MEMORY_SCOPE_AGENT);
}

// one-entry parity poll: the poll IS the data read (0 fails both tests -> "reset")
__device__ __forceinline__ float pollsgn(const float* p, int neg) {
  for (;;) {
    float v = aloadf(p);
    if (neg ? (v < 0.0f) : (v > 0.0f)) return v;
    __builtin_amdgcn_s_sleep(1);
  }
}
__device__ __forceinline__ float pollp(const float* p) {   // ready: >= 0 (reset -1)
  for (;;) {
    float v = aloadf(p);
    if (v >= 0.0f) return v;
    __builtin_amdgcn_s_sleep(1);
  }
}
__device__ __forceinline__ int polli(const int* p) {       // ready: >= 0 (reset -1)
  for (;;) {
    int v = aloadi(p);
    if (v >= 0) return v;
    __builtin_amdgcn_s_sleep(1);
  }
}
__device__ __forceinline__ float pollz(const float* p) {   // ready: > -1e29 (reset -1e30)
  for (;;) {
    float v = aloadf(p);
    if (v > -1e29f) return v;
    __builtin_amdgcn_s_sleep(1);
  }
}

// mdesc = Wp @ desc + bp for BOTH descriptors; writes transpose too. grid (4,64,2)
__global__ __launch_bounds__(TPB) void k_mdesc(const float* __restrict__ Wp,
                                               const float* __restrict__ bp,
                                               const float* __restrict__ desc0,
                                               const float* __restrict__ desc1,
                                               float* __restrict__ md0,
                                               float* __restrict__ md0T,
                                               float* __restrict__ md1,
                                               float* __restrict__ md1T) {
  int j = blockIdx.x * TPB + threadIdx.x;
  int d0 = blockIdx.y * 4;
  const float* desc = blockIdx.z ? desc1 : desc0;
  float* md  = blockIdx.z ? md1  : md0;
  float* mdT = blockIdx.z ? md1T : md0T;
  float acc[4] = {0.f, 0.f, 0.f, 0.f};
  for (int k = 0; k < Dd; ++k) {
    float v = desc[(size_t)k * Nn + j];
#pragma unroll
    for (int r = 0; r < 4; ++r) acc[r] += Wp[(size_t)(d0 + r) * Dd + k] * v;
  }
#pragma unroll
  for (int r = 0; r < 4; ++r) {
    acc[r] += bp[d0 + r];
    md[(size_t)(d0 + r) * Nn + j] = acc[r];
  }
  *(float4*)&mdT[(size_t)j * Dd + d0] = make_float4(acc[0], acc[1], acc[2], acc[3]);
}

// ---- bodies shared between split and merged launches ----
__device__ __forceinline__ void h_body(int bx, int by, int bz,
                                       const float* __restrict__ W1,
                                       const float* __restrict__ md0,
                                       const float* __restrict__ md1,
                                       float* __restrict__ hA,
                                       float* __restrict__ hBt) {
  int j = bx * TPB + threadIdx.x;
  int o = by;
  const float* md = bz ? md1 : md0;
  const float* w = W1 + (size_t)o * 512 + bz * 256;
  float acc = 0.f;
  for (int d = 0; d < Dd; ++d) acc += md[(size_t)d * Nn + j] * w[d];
  if (bz == 0) hA[(size_t)j * 64 + o] = acc;
  else         hBt[(size_t)o * Nn + j] = acc;
}

__device__ __forceinline__ void buildK_body(int bx, int by,
                                            const float* __restrict__ md0T,
                                            const float* __restrict__ md1,
                                            float* __restrict__ K,
                                            float* __restrict__ KT) {
  int j = bx * TPB + threadIdx.x;
  int i0 = by * 8;
  __shared__ float m0s[8][Dd];
  for (int idx = threadIdx.x; idx < 8 * Dd; idx += TPB) {
    int r = idx >> 8, d = idx & 255;
    m0s[r][d] = md0T[(size_t)(i0 + r) * Dd + d];
  }
  __syncthreads();
  float acc[8] = {0.f, 0.f, 0.f, 0.f, 0.f, 0.f, 0.f, 0.f};
  for (int d = 0; d < Dd; ++d) {
    float mv = md1[(size_t)d * Nn + j];
#pragma unroll
    for (int r = 0; r < 8; ++r) acc[r] += m0s[r][d] * mv;
  }
  float vr[8];
#pragma unroll
  for (int r = 0; r < 8; ++r) {
    vr[r] = expf(acc[r] * 0.0625f);
    K[(size_t)(i0 + r) * LDKc + j] = vr[r];
  }
  *(float4*)&KT[(size_t)j * LDKc + i0]     = make_float4(vr[0], vr[1], vr[2], vr[3]);
  *(float4*)&KT[(size_t)j * LDKc + i0 + 4] = make_float4(vr[4], vr[5], vr[6], vr[7]);
}

// split launches (path A)
__global__ __launch_bounds__(TPB) void k_h(const float* __restrict__ W1,
                                           const float* __restrict__ md0,
                                           const float* __restrict__ md1,
                                           float* __restrict__ hA,
                                           float* __restrict__ hBt) {
  h_body(blockIdx.x, blockIdx.y, blockIdx.z, W1, md0, md1, hA, hBt);
}
__global__ __launch_bounds__(TPB) void k_buildK(const float* __restrict__ md0T,
                                                const float* __restrict__ md1,
                                                float* __restrict__ K,
                                                float* __restrict__ KT) {
  buildK_body(blockIdx.x, blockIdx.y, md0T, md1, K, KT);
}
// merged h + buildK (path B): 1024 flat blocks; both depend only on mdesc.
__global__ __launch_bounds__(TPB) void k_hbk(const float* __restrict__ W1,
                                             const float* __restrict__ md0,
                                             const float* __restrict__ md1,
                                             const float* __restrict__ md0T,
                                             float* __restrict__ hA,
                                             float* __restrict__ hBt,
                                             float* __restrict__ K,
                                             float* __restrict__ KT) {
  int fb = blockIdx.x;
  if (fb < 512) {
    int z = fb >> 8, rem = fb & 255;
    h_body(rem & 3, rem >> 2, z, W1, md0, md1, hA, hBt);
  } else {
    int bb = fb - 512;
    buildK_body(bb & 3, bb >> 2, md0T, md1, K, KT);
  }
}

// attn[i,j] = b2 + sum_o W2[o]*relu(hA[i,o]+hBt[o,j]+b1[o]). grid (4,256)
__global__ __launch_bounds__(TPB) void k_attn(const float* __restrict__ hA,
                                              const float* __restrict__ hBt,
                                              const float* __restrict__ W2,
                                              const float* __restrict__ b1,
                                              const float* __restrict__ b2,
                                              float* __restrict__ attn) {
  int j = blockIdx.x * TPB + threadIdx.x;
  int i0 = blockIdx.y * 4;
  float bias = b2[0];
  float acc[4] = {bias, bias, bias, bias};
  for (int o = 0; o < 64; ++o) {
    float hb = hBt[(size_t)o * Nn + j] + b1[o];
    float w = W2[o];
#pragma unroll
    for (int r = 0; r < 4; ++r) {
      float t = hA[(size_t)(i0 + r) * 64 + o] + hb;
      acc[r] += w * fmaxf(t, 0.f);
    }
  }
#pragma unroll
  for (int r = 0; r < 4; ++r) attn[(size_t)(i0 + r) * Nn + j] = acc[r];
}

// merged: row stats (0..1023) + column partial stats (1024..1087) + W transposes
// (1088..1407) + sync-buffer resets (1408..1411). grid 1412
__global__ __launch_bounds__(TPB) void k_stats(const float* __restrict__ attn,
                                               float* __restrict__ rowM,
                                               float* __restrict__ rowS,
                                               float* __restrict__ cmp,
                                               float* __restrict__ csp,
                                               const float* __restrict__ Wz1,
                                               const float* __restrict__ Wz2,
                                               float* __restrict__ Wz1T,
                                               float* __restrict__ Wz2T,
                                               float* __restrict__ av,
                                               float* __restrict__ bv,
                                               float* __restrict__ rinvb,
                                               int* __restrict__ idx0,
                                               float* __restrict__ max0,
                                               int* __restrict__ idx1,
                                               float* __restrict__ zAr,
                                               float* __restrict__ zBr) {
  int t = threadIdx.x;
  if (blockIdx.x < 1024) {
    int i = blockIdx.x;
    const float* row = attn + (size_t)i * Nn;
    float m = -INFINITY;
    for (int q = 0; q < 4; ++q) m = fmaxf(m, row[t + q * TPB]);
    __shared__ float red[TPB];
    red[t] = m; __syncthreads();
    for (int s = TPB / 2; s > 0; s >>= 1) {
      if (t < s) red[t] = fmaxf(red[t], red[t + s]);
      __syncthreads();
    }
    m = red[0]; __syncthreads();
    float ssum = 0.f;
    for (int q = 0; q < 4; ++q) ssum += expf(row[t + q * TPB] - m);
    red[t] = ssum; __syncthreads();
    for (int s = TPB / 2; s > 0; s >>= 1) {
      if (t < s) red[t] += red[t + s];
      __syncthreads();
    }
    if (t == 0) { rowM[i] = m; rowS[i] = red[0]; }
  } else if (blockIdx.x < 1088) {
    int flat = blockIdx.x - 1024;     // 0..63
    int jx = flat & 3, c = flat >> 2;
    int j = jx * TPB + t, i0 = c * 64;
    float m = -INFINITY;
    for (int q = 0; q < 64; ++q) m = fmaxf(m, attn[(size_t)(i0 + q) * Nn + j]);
    float s = 0.f;
    for (int q = 0; q < 64; ++q) s += expf(attn[(size_t)(i0 + q) * Nn + j] - m);
    cmp[(size_t)c * Nn + j] = m;
    csp[(size_t)c * Nn + j] = s;
  } else if (blockIdx.x < 1408) {
    int b = blockIdx.x - 1088;        // 0..319
    if (b < 256) Wz1T[(size_t)t * 256 + b] = Wz1[(size_t)b * 256 + t];
    else {
      int o = b - 256;
      Wz2T[(size_t)t * 64 + o] = Wz2[(size_t)o * 256 + t];
    }
  } else {
    int idx = (blockIdx.x - 1408) * TPB + t;   // 0..1023
    av[idx] = 0.0f; bv[idx] = 0.0f; rinvb[idx] = -1.0f;
    idx0[idx] = -1; idx1[idx] = -1; max0[idx] = -1.0f;
    zAr[idx] = -1e30f; zBr[idx] = -1e30f;
    if (idx == 0) { av[1024] = 0.0f; bv[1024] = 0.0f; rinvb[1024] = -1.0f; }
  }
}

// zfeat partials with on-the-fly prob + inline colcomb (side 1). 8 rows/block.
// grid (128, 2, 2). P tile in LDS.
__global__ __launch_bounds__(TPB) void k_zfeat_part(const float* __restrict__ attn,
                                                    const float* __restrict__ rowM,
                                                    const float* __restrict__ rowS,
                                                    const float* __restrict__ cmp,
                                                    const float* __restrict__ csp,
                                                    const float* __restrict__ md0T,
                                                    const float* __restrict__ md1T,
                                                    float* __restrict__ part) {
  int d = threadIdx.x;
  int r0 = blockIdx.x * 8;
  int jc = blockIdx.y;
  int side = blockIdx.z;
  int j0 = jc * 512;
  __shared__ float P[8][512];
  __shared__ float colMs[8], colSs[8];
  if (side == 1 && threadIdx.x < 8) {
    int j = r0 + threadIdx.x;
    float m = -INFINITY;
    for (int c = 0; c < 16; ++c) m = fmaxf(m, cmp[(size_t)c * Nn + j]);
    float s = 0.f;
    for (int c = 0; c < 16; ++c) s += csp[(size_t)c * Nn + j] * expf(cmp[(size_t)c * Nn + j] - m);
    colMs[threadIdx.x] = m; colSs[threadIdx.x] = s;
  }
  __syncthreads();
  if (side == 0) {
    for (int idx = threadIdx.x; idx < 8 * 512; idx += TPB) {
      int r = idx >> 9, jj = idx & 511;
      int i = r0 + r;
      P[r][jj] = expf(attn[(size_t)i * Nn + j0 + jj] - rowM[i]) / rowS[i];
    }
  } else {
    for (int idx = threadIdx.x; idx < 8 * 512; idx += TPB) {
      int r = idx & 7, ii = idx >> 3;
      P[r][ii] = expf(attn[(size_t)(j0 + ii) * Nn + (r0 + r)] - colMs[r]) / colSs[r];
    }
  }
  __syncthreads();
  const float* mdT = side ? md0T : md1T;
  float acc[8] = {0.f, 0.f, 0.f, 0.f, 0.f, 0.f, 0.f, 0.f};
  for (int jj = 0; jj < 512; ++jj) {
    float mv = mdT[(size_t)(j0 + jj) * Dd + d];
#pragma unroll
    for (int r = 0; r < 8; ++r) acc[r] += P[r][jj] * mv;
  }
  float* dst = part + (size_t)(side * 2 + jc) * ((size_t)Nn * Dd);
#pragma unroll
  for (int r = 0; r < 8; ++r) dst[(size_t)(r0 + r) * Dd + d] = acc[r];
}

// standalone zmlp (path A), 8 rows per block. grid (128, 2)
__global__ __launch_bounds__(TPB) void k_zmlp(const float* __restrict__ part,
                                              const float* __restrict__ Wz1T,
                                              const float* __restrict__ bz1,
                                              const float* __restrict__ Wz2T,
                                              const float* __restrict__ bz2,
                                              const float* __restrict__ Wz3,
                                              const float* __restrict__ bz3,
                                              float* __restrict__ zAr,
                                              float* __restrict__ zBr) {
  int i0 = blockIdx.x * 8;
  int which = blockIdx.y;
  int t = threadIdx.x;
  __shared__ float xs[8][Dd];
  __shared__ float h1[8][Dd];
  __shared__ float h2[8][64];
  const float* p0 = part + (size_t)(which * 2) * ((size_t)Nn * Dd);
  const float* p1 = p0 + (size_t)Nn * Dd;
  for (int idx = t; idx < 8 * Dd; idx += TPB) {
    int r = idx >> 8, d = idx & 255;
    size_t off = (size_t)(i0 + r) * Dd + d;
    xs[r][d] = p0[off] + p1[off];
  }
  __syncthreads();
  float a1[8];
  float bb = bz1[t];
#pragma unroll
  for (int r = 0; r < 8; ++r) a1[r] = bb;
  for (int k = 0; k < Dd; ++k) {
    float w = Wz1T[(size_t)k * Dd + t];
#pragma unroll
    for (int r = 0; r < 8; ++r) a1[r] += w * xs[r][k];
  }
#pragma unroll
  for (int r = 0; r < 8; ++r) h1[r][t] = fmaxf(a1[r], 0.f);
  __syncthreads();
  {
    int o = t & 63, rg = (t >> 6) * 2;
    float b2v = bz2[o];
    float a20 = b2v, a21 = b2v;
    for (int k = 0; k < Dd; ++k) {
      float w = Wz2T[(size_t)k * 64 + o];
      a20 += w * h1[rg][k];
      a21 += w * h1[rg + 1][k];
    }
    h2[rg][o] = fmaxf(a20, 0.f);
    h2[rg + 1][o] = fmaxf(a21, 0.f);
  }
  __syncthreads();
  int wv = t >> 6, l = t & 63;
  float* z = which ? zBr : zAr;
#pragma unroll
  for (int s = 0; s < 2; ++s) {
    int r = wv * 2 + s;
    float p = Wz3[l] * h2[r][l];
#pragma unroll
    for (int off = 32; off > 0; off >>= 1) p += __shfl_down(p, off);
    if (l == 0) z[i0 + r] = p + bz3[0];
  }
}

// Dataflow Sinkhorn + optional fused zmlp head + fused epilogue + early exit.
// grid NB x PT. Wave w of block b owns row b*16+w. When do_zmlp!=0, the block first
// computes zA/zB rows b*16..b*16+15 (exactly the rows it needs for its dustbin edges).
__global__ __launch_bounds__(PT) void k_sink_flow2(
    const float* __restrict__ K, const float* __restrict__ KT,
    const float* part, const float* __restrict__ Wz1T,
    const float* __restrict__ bz1, const float* __restrict__ Wz2T,
    const float* __restrict__ bz2, const float* __restrict__ Wz3,
    const float* __restrict__ bz3,
    float* __restrict__ zAr, float* __restrict__ zBr,
    float* __restrict__ av, float* __restrict__ bv, float* __restrict__ rinvb,
    int* __restrict__ idx0, float* __restrict__ max0, int* __restrict__ idx1,
    float* __restrict__ out, int do_zmlp) {
  const int bid = blockIdx.x;
  const int t = threadIdx.x;
  const int w = t >> 6, l = t & 63;
  const int row = bid * 16 + w;
  const bool extra = (bid == 0 && w == 0);
  const float MU = 1.0f / 2048.0f;
  const float TOL = 1e-5f;
  const float E1 = 2.7182818284590452f;  // exp(alpha=1)

  __shared__ float smem[18432];          // 72KB overlay: zmlp scratch, then flow arrays
  __shared__ int chgflag;

  // ---- optional zmlp phase: rows {zA,zB}[bid*16 .. bid*16+15] ----
  if (do_zmlp) {
    float (*zxs)[Dd] = (float(*)[Dd])smem;            // [32][256]
    float (*zh1)[Dd] = (float(*)[Dd])(smem + 8192);   // [32][256]
    float (*zh2)[64] = (float(*)[64])(smem + 16384);  // [32][64]
    for (int idx = t; idx < 32 * Dd; idx += PT) {
      int r = idx >> 8, d = idx & 255;
      int side = r >> 4;
      const float* p0 = part + (size_t)(side * 2) * ((size_t)Nn * Dd);
      const float* p1 = p0 + (size_t)Nn * Dd;
      size_t off = (size_t)(bid * 16 + (r & 15)) * Dd + d;
      zxs[r][d] = p0[off] + p1[off];
    }
    __syncthreads();
    {
      int u = t & 255, g = t >> 8;
      float a1[8];
      float bb = bz1[u];
#pragma unroll
      for (int r = 0; r < 8; ++r) a1[r] = bb;
      for (int k = 0; k < Dd; ++k) {
        float wv = Wz1T[(size_t)k * Dd + u];
#pragma unroll
        for (int r = 0; r < 8; ++r) a1[r] += wv * zxs[8 * g + r][k];
      }
#pragma unroll
      for (int r = 0; r < 8; ++r) zh1[8 * g + r][u] = fmaxf(a1[r], 0.f);
    }
    __syncthreads();
    {
      int o = t & 63, rp = (t >> 6) * 2;
      float b2v = bz2[o];
      float a20 = b2v, a21 = b2v;
      for (int k = 0; k < Dd; ++k) {
        float wv = Wz2T[(size_t)k * 64 + o];
        a20 += wv * zh1[rp][k];
        a21 += wv * zh1[rp + 1][k];
      }
      zh2[rp][o] = fmaxf(a20, 0.f);
      zh2[rp + 1][o] = fmaxf(a21, 0.f);
    }
    __syncthreads();
#pragma unroll
    for (int s = 0; s < 2; ++s) {
      int r = w * 2 + s;
      float p = Wz3[l] * zh2[r][l];
#pragma unroll
      for (int off = 32; off > 0; off >>= 1) p += __shfl_down(p, off);
      if (l == 0) {
        float val = p + bz3[0];
        int gr = bid * 16 + (r & 15);
        if (r < 16) astoref(&zAr[gr], val);
        else        astoref(&zBr[gr], val);
      }
    }
    __syncthreads();   // release smem for flow arrays
  }

  // ---- flow arrays overlay ----
  float* xsA = smem;                // [LDKc]
  float* xsB = smem + LDKc;         // [LDKc]
  float* rsv = smem + 2 * LDKc;     // [LDKc]
  int*   i0s = (int*)(smem + 3 * LDKc);
  int*   i1s = i0s + Nn;
  int*   v0s = i1s + Nn;
  float* msg = (float*)(v0s + Nn);

  const float* kp = K  + (size_t)row * LDKc;
  const float* tp = KT + (size_t)row * LDKc;
  float kr[16], tr[16];
#pragma unroll
  for (int q = 0; q < 16; ++q) { kr[q] = kp[l + 64 * q]; tr[q] = tp[l + 64 * q]; }
  const float k16 = (l == 0) ? expf(pollz(&zAr[row])) : 0.0f;   // K[row][1024]
  const float t16 = (l == 0) ? expf(pollz(&zBr[row])) : 0.0f;   // KT[row][1024]
  float k2[16], t2[16];
  float k216 = 0.0f, t216 = 0.0f;
#pragma unroll
  for (int q = 0; q < 16; ++q) { k2[q] = 0.0f; t2[q] = 0.0f; }
  if (extra) {
#pragma unroll
    for (int q = 0; q < 16; ++q) {
      k2[q] = expf(pollz(&zBr[l + 64 * q]));   // K[1024][j]
      t2[q] = expf(pollz(&zAr[l + 64 * q]));   // KT[1024][i]
    }
    if (l == 0) { k216 = E1; t216 = E1; }
  }

  float prevB = -1.0f, prevB1024 = -1.0f;

  // ---- a gen0 = mu / (K · 1) ----
  {
    float acc = k16;
#pragma unroll
    for (int q = 0; q < 16; ++q) acc += kr[q];
#pragma unroll
    for (int off = 32; off > 0; off >>= 1) acc += __shfl_xor(acc, off);
    if (l == 0) astoref(&av[row], MU / acc);
    if (extra) {
      float a2 = k216;
#pragma unroll
      for (int q = 0; q < 16; ++q) a2 += k2[q];
#pragma unroll
      for (int off = 32; off > 0; off >>= 1) a2 += __shfl_xor(a2, off);
      if (l == 0) astoref(&av[1024], 0.5f / a2);
    }
  }

  for (int it = 0; it < SINK_ITERS; ++it) {
    const int sg = it & 1;
    xsA[t] = fabsf(pollsgn(&av[t], sg));
    if (t == 0) xsA[1024] = fabsf(pollsgn(&av[1024], sg));
    __syncthreads();                        // S1
    if (t == 0) chgflag = 0;
    // b gen it = nu / (KT a)
    {
      float acc = t16 * xsA[1024];
#pragma unroll
      for (int q = 0; q < 16; ++q) acc += tr[q] * xsA[l + 64 * q];
#pragma unroll
      for (int off = 32; off > 0; off >>= 1) acc += __shfl_xor(acc, off);
      if (l == 0) { float r = MU / acc; astoref(&bv[row], sg ? -r : r); }
      if (extra) {
        float a2 = t216 * xsA[1024];
#pragma unroll
        for (int q = 0; q < 16; ++q) a2 += t2[q] * xsA[l + 64 * q];
#pragma unroll
        for (int off = 32; off > 0; off >>= 1) a2 += __shfl_xor(a2, off);
        if (l == 0) { float r = 0.5f / a2; astoref(&bv[1024], sg ? -r : r); }
      }
    }
    // stage |b| + convergence test vs previous iteration
    {
      float nb = fabsf(pollsgn(&bv[t], sg));
      xsB[t] = nb;
      bool ch = fabsf(nb - prevB) > TOL * nb;
      prevB = nb;
      if (t == 0) {
        float nb2 = fabsf(pollsgn(&bv[1024], sg));
        xsB[1024] = nb2;
        ch |= fabsf(nb2 - prevB1024) > TOL * nb2;
        prevB1024 = nb2;
      }
      if (ch) chgflag = 1;                  // benign same-value race
    }
    __syncthreads();                        // S2
    if (chgflag == 0) break;                // identical data everywhere -> uniform break
    // a gen it+1 = mu / (K b)
    if (it + 1 < SINK_ITERS) {
      const int sn = (it + 1) & 1;
      float acc = k16 * xsB[1024];
#pragma unroll
      for (int q = 0; q < 16; ++q) acc += kr[q] * xsB[l + 64 * q];
#pragma unroll
      for (int off = 32; off > 0; off >>= 1) acc += __shfl_xor(acc, off);
      if (l == 0) { float r = MU / acc; astoref(&av[row], sn ? -r : r); }
      if (extra) {
        float a2 = k216 * xsB[1024];
#pragma unroll
        for (int q = 0; q < 16; ++q) a2 += k2[q] * xsB[l + 64 * q];
#pragma unroll
        for (int off = 32; off > 0; off >>= 1) a2 += __shfl_xor(a2, off);
        if (l == 0) { float r = 0.5f / a2; astoref(&av[1024], sn ? -r : r); }
      }
    }
  }

  // ---- rinv = 1/(K·b) ----
  {
    float acc = k16 * xsB[1024];
#pragma unroll
    for (int q = 0; q < 16; ++q) acc += kr[q] * xsB[l + 64 * q];
#pragma unroll
    for (int off = 32; off > 0; off >>= 1) acc += __shfl_xor(acc, off);
    if (l == 0) astoref(&rinvb[row], 1.0f / acc);
    if (extra) {
      float a2 = k216 * xsB[1024];
#pragma unroll
      for (int q = 0; q < 16; ++q) a2 += k2[q] * xsB[l + 64 * q];
#pragma unroll
      for (int off = 32; off > 0; off >>= 1) a2 += __shfl_xor(a2, off);
      if (l == 0) astoref(&rinvb[1024], 1.0f / a2);
    }
  }
  rsv[t] = pollp(&rinvb[t]);
  if (t == 0) rsv[1024] = pollp(&rinvb[1024]);
  __syncthreads();

  // ---- S rows + row argmax + col argmax ----
  float* Sbase = out + 4096;
  {
    float ri = rsv[row];
    float* srow = Sbase + (size_t)row * Mm;
    float bm = -1.0f; int bj = 0;
#pragma unroll
    for (int q = 0; q < 16; ++q) {
      int j = l + 64 * q;
      float s = (kr[q] * xsB[j]) * ri;
      srow[j] = s;
      if (s > bm) { bm = s; bj = j; }
    }
    if (l == 0) srow[1024] = (k16 * xsB[1024]) * ri;
#pragma unroll
    for (int off = 32; off > 0; off >>= 1) {
      float om = __shfl_xor(bm, off);
      int oj = __shfl_xor(bj, off);
      if (om > bm || (om == bm && oj < bj)) { bm = om; bj = oj; }
    }
    if (l == 0) { astorei(&idx0[row], bj); astoref(&max0[row], bm); }
    float bc = xsB[row];
    float cm = -1.0f; int ci = 0;
#pragma unroll
    for (int q = 0; q < 16; ++q) {
      int i = l + 64 * q;
      float v = (tr[q] * bc) * rsv[i];
      if (v > cm) { cm = v; ci = i; }
    }
#pragma unroll
    for (int off = 32; off > 0; off >>= 1) {
      float om = __shfl_xor(cm, off);
      int oi = __shfl_xor(ci, off);
      if (om > cm || (om == cm && oi < ci)) { cm = om; ci = oi; }
    }
    if (l == 0) astorei(&idx1[row], ci);
    if (extra) {  // S row 1024
      float ri2 = rsv[1024];
      float* sr2 = Sbase + (size_t)Nn * Mm;
#pragma unroll
      for (int q = 0; q < 16; ++q) {
        int j = l + 64 * q;
        sr2[j] = (k2[q] * xsB[j]) * ri2;
      }
      if (l == 0) sr2[1024] = (k216 * xsB[1024]) * ri2;
    }
  }

  // ---- mutual matching (block 0) ----
  if (bid == 0) {
    int j0  = polli(&idx0[t]);
    int i1v = polli(&idx1[t]);
    float mr = pollp(&max0[t]);
    i0s[t] = j0; i1s[t] = i1v;
    __syncthreads();
    bool mut0 = (i1s[j0] == t);
    float m0 = mut0 ? expf(mr) : 0.0f;
    bool val0 = mut0 && (m0 > 0.2f);
    msg[t] = m0; v0s[t] = val0 ? 1 : 0;
    out[t] = val0 ? (float)j0 : -1.0f;   // indices0
    out[2048 + t] = m0;                   // mscores0
    __syncthreads();
    bool mut1 = (i0s[i1v] == t);
    float m1 = mut1 ? msg[i1v] : 0.0f;
    bool val1 = mut1 && (v0s[i1v] != 0);
    out[1024 + t] = val1 ? (float)i1v : -1.0f;  // indices1
    out[3072 + t] = m1;                          // mscores1
  }
}

extern "C" void kernel_launch(void* const* d_in, const int* in_sizes, int n_in,
                              void* d_out, int out_size, void* d_ws, size_t ws_size,
                              hipStream_t stream) {
  (void)in_sizes; (void)n_in; (void)out_size;
  const float* desc0 = (const float*)d_in[0];
  const float* desc1 = (const float*)d_in[1];
  const float* Wp    = (const float*)d_in[2];
  const float* bp    = (const float*)d_in[3];
  const float* W1    = (const float*)d_in[4];
  const float* b1    = (const float*)d_in[5];
  const float* W2    = (const float*)d_in[6];
  const float* b2    = (const float*)d_in[7];
  const float* Wz1   = (const float*)d_in[8];
  const float* bz1   = (const float*)d_in[9];
  const float* Wz2   = (const float*)d_in[10];
  const float* bz2   = (const float*)d_in[11];
  const float* Wz3   = (const float*)d_in[12];
  const float* bz3   = (const float*)d_in[13];
  float* ws  = (float*)d_ws;
  float* out = (float*)d_out;
  dim3 blk(TPB);

  const bool pathB = ws_size >= NEED_B_FLOATS * sizeof(float);
  float* Kp  = ws + (pathB ? OF_K_B : OF_K_A);
  float* KTp = Kp + (size_t)Mm * LDKc;

  k_mdesc<<<dim3(4, 64, 2), blk, 0, stream>>>(Wp, bp, desc0, desc1,
                                              ws + OF_MD0, ws + OF_MD0T,
                                              ws + OF_MD1, ws + OF_MD1T);
  if (pathB) {
    // h and buildK both depend only on mdesc -> one merged launch (K in own region)
    k_hbk<<<dim3(1024), blk, 0, stream>>>(W1, ws + OF_MD0, ws + OF_MD1, ws + OF_MD0T,
                                          ws + OF_HA, ws + OF_HBT, Kp, KTp);
  } else {
    k_h<<<dim3(4, 64, 2), blk, 0, stream>>>(W1, ws + OF_MD0, ws + OF_MD1,
                                            ws + OF_HA, ws + OF_HBT);
  }
  k_attn<<<dim3(4, 256), blk, 0, stream>>>(ws + OF_HA, ws + OF_HBT, W2, b1, b2,
                                           ws + OF_ATTN);
  k_stats<<<dim3(1412), blk, 0, stream>>>(ws + OF_ATTN, ws + OF_ROWM, ws + OF_ROWS,
                                          ws + OF_CMP, ws + OF_CSP,
                                          Wz1, Wz2, ws + OF_WZ1T, ws + OF_WZ2T,
                                          ws + OF_AV, ws + OF_BV, ws + OF_RINV,
                                          (int*)(ws + OF_IDX0), ws + OF_MAX0,
                                          (int*)(ws + OF_IDX1),
                                          ws + OF_ZA, ws + OF_ZB);
  k_zfeat_part<<<dim3(128, 2, 2), blk, 0, stream>>>(ws + OF_ATTN,
                                                    ws + OF_ROWM, ws + OF_ROWS,
                                                    ws + OF_CMP, ws + OF_CSP,
                                                    ws + OF_MD0T, ws + OF_MD1T,
                                                    ws + OF_PART);
  if (!pathB) {
    k_zmlp<<<dim3(128, 2), blk, 0, stream>>>(ws + OF_PART, ws + OF_WZ1T, bz1,
                                             ws + OF_WZ2T, bz2, Wz3, bz3,
                                             ws + OF_ZA, ws + OF_ZB);
    // buildK last: clobbers attn/part region (both dead by now) in layout A
    k_buildK<<<dim3(4, 128), blk, 0, stream>>>(ws + OF_MD0T, ws + OF_MD1, Kp, KTp);
  }
  k_sink_flow2<<<dim3(NB), dim3(PT), 0, stream>>>(
      Kp, KTp, ws + OF_PART, ws + OF_WZ1T, bz1, ws + OF_WZ2T, bz2, Wz3, bz3,
      ws + OF_ZA, ws + OF_ZB,
      ws + OF_AV, ws + OF_BV, ws + OF_RINV,
      (int*)(ws + OF_IDX0), ws + OF_MAX0, (int*)(ws + OF_IDX1),
      out, pathB ? 1 : 0);
}

// Round 12
// 196.403 us; speedup vs baseline: 1.1150x; 1.1150x over previous
//
#include <hip/hip_runtime.h>
#include <math.h>

#define TPB 256

constexpr int Dd = 256;
constexpr int Nn = 1024;
constexpr int Mm = 1025;      // Nn + 1 (with dustbin)
constexpr int LDKc = 1040;    // padded row stride for K / KT (16-float aligned)
constexpr int SINK_ITERS = 100;
constexpr int NB  = 64;       // flow blocks
constexpr int PT  = 1024;     // threads per flow block (16 waves, 1 wave = 1 row)

// ---- workspace layout (float offsets) ----
constexpr size_t OF_MD0   = 0;
constexpr size_t OF_MD1   = OF_MD0  + (size_t)Dd*Nn;
constexpr size_t OF_MD0T  = OF_MD1  + (size_t)Dd*Nn;
constexpr size_t OF_MD1T  = OF_MD0T + (size_t)Dd*Nn;
constexpr size_t OF_HA    = OF_MD1T + (size_t)Dd*Nn;
constexpr size_t OF_HBT   = OF_HA   + (size_t)Nn*64;
constexpr size_t OF_WZ1T  = OF_HBT  + (size_t)Nn*64;
constexpr size_t OF_WZ2T  = OF_WZ1T + (size_t)Dd*Dd;
constexpr size_t OF_ZA    = OF_WZ2T + (size_t)64*Dd;
constexpr size_t OF_ZB    = OF_ZA   + Nn;
constexpr size_t OF_ROWM  = OF_ZB   + Nn;
constexpr size_t OF_ROWS  = OF_ROWM + Nn;
constexpr size_t OF_CMP   = OF_ROWS + Nn;        // 16 x 1024 column partial max
constexpr size_t OF_CSP   = OF_CMP  + (size_t)16*Nn;
constexpr size_t OF_AV    = OF_CSP  + (size_t)16*Nn;  // a vector (sign-parity; reset 0)
constexpr size_t OF_BV    = OF_AV   + LDKc;           // b vector (sign-parity; reset 0)
constexpr size_t OF_RINV  = OF_BV   + LDKc;           // 1/rowsum; reset -1, ready >= 0
constexpr size_t OF_IDX0  = OF_RINV + LDKc;           // int; reset -1, ready >= 0
constexpr size_t OF_MAX0  = OF_IDX0 + Nn;             // reset -1, ready >= 0
constexpr size_t OF_IDX1  = OF_MAX0 + Nn;             // int; reset -1
constexpr size_t OF_ATTN  = OF_IDX1 + Nn;
constexpr size_t OF_PART  = OF_ATTN + (size_t)Nn*Nn;  // zfeat partials (4 x 256K floats)
// K/KT placement: path A aliases attn+part (buildK runs late); path B is a separate
// region after part (buildK overlaps k_h in the merged k_hbk). Chosen from ws_size.
constexpr size_t OF_K_A   = OF_ATTN;
constexpr size_t OF_K_B   = OF_PART + (size_t)4*Nn*Dd;
constexpr size_t NEED_B_FLOATS = OF_K_B + (size_t)2*Mm*LDKc;

// ---------- agent-scope (coherence-point) access helpers ----------
__device__ __forceinline__ float aloadf(const float* p) {
  return __hip_atomic_load((float*)p, __ATOMIC_RELAXED, __HIP_MEMORY_SCOPE_AGENT);
}
__device__ __forceinline__ int aloadi(const int* p) {
  return __hip_atomic_load((int*)p, __ATOMIC_RELAXED, __HIP_MEMORY_SCOPE_AGENT);
}
__device__ __forceinline__ void astoref(float* p, float v) {
  __hip_atomic_store(p, v, __ATOMIC_RELAXED, __HIP_MEMORY_SCOPE_AGENT);
}
__device__ __forceinline__ void astorei(int* p, int v) {
  __hip_atomic_store(p, v, __ATOMIC_RELAXED, __HIP_MEMORY_SCOPE_AGENT);
}

// one-entry parity poll: the poll IS the data read (0 fails both tests -> "reset")
__device__ __forceinline__ float pollsgn(const float* p, int neg) {
  for (;;) {
    float v = aloadf(p);
    if (neg ? (v < 0.0f) : (v > 0.0f)) return v;
    __builtin_amdgcn_s_sleep(1);
  }
}
__device__ __forceinline__ float pollp(const float* p) {   // ready: >= 0 (reset -1)
  for (;;) {
    float v = aloadf(p);
    if (v >= 0.0f) return v;
    __builtin_amdgcn_s_sleep(1);
  }
}
__device__ __forceinline__ int polli(const int* p) {       // ready: >= 0 (reset -1)
  for (;;) {
    int v = aloadi(p);
    if (v >= 0) return v;
    __builtin_amdgcn_s_sleep(1);
  }
}

// mdesc = Wp @ desc + bp for BOTH descriptors; writes transpose too. grid (4,64,2)
__global__ __launch_bounds__(TPB) void k_mdesc(const float* __restrict__ Wp,
                                               const float* __restrict__ bp,
                                               const float* __restrict__ desc0,
                                               const float* __restrict__ desc1,
                                               float* __restrict__ md0,
                                               float* __restrict__ md0T,
                                               float* __restrict__ md1,
                                               float* __restrict__ md1T) {
  int j = blockIdx.x * TPB + threadIdx.x;
  int d0 = blockIdx.y * 4;
  const float* desc = blockIdx.z ? desc1 : desc0;
  float* md  = blockIdx.z ? md1  : md0;
  float* mdT = blockIdx.z ? md1T : md0T;
  float acc[4] = {0.f, 0.f, 0.f, 0.f};
  for (int k = 0; k < Dd; ++k) {
    float v = desc[(size_t)k * Nn + j];
#pragma unroll
    for (int r = 0; r < 4; ++r) acc[r] += Wp[(size_t)(d0 + r) * Dd + k] * v;
  }
#pragma unroll
  for (int r = 0; r < 4; ++r) {
    acc[r] += bp[d0 + r];
    md[(size_t)(d0 + r) * Nn + j] = acc[r];
  }
  *(float4*)&mdT[(size_t)j * Dd + d0] = make_float4(acc[0], acc[1], acc[2], acc[3]);
}

// ---- bodies shared between split and merged launches ----
__device__ __forceinline__ void h_body(int bx, int by, int bz,
                                       const float* __restrict__ W1,
                                       const float* __restrict__ md0,
                                       const float* __restrict__ md1,
                                       float* __restrict__ hA,
                                       float* __restrict__ hBt) {
  int j = bx * TPB + threadIdx.x;
  int o = by;
  const float* md = bz ? md1 : md0;
  const float* w = W1 + (size_t)o * 512 + bz * 256;
  float acc = 0.f;
  for (int d = 0; d < Dd; ++d) acc += md[(size_t)d * Nn + j] * w[d];
  if (bz == 0) hA[(size_t)j * 64 + o] = acc;
  else         hBt[(size_t)o * Nn + j] = acc;
}

__device__ __forceinline__ void buildK_body(int bx, int by,
                                            const float* __restrict__ md0T,
                                            const float* __restrict__ md1,
                                            float* __restrict__ K,
                                            float* __restrict__ KT) {
  int j = bx * TPB + threadIdx.x;
  int i0 = by * 8;
  __shared__ float m0s[8][Dd];
  for (int idx = threadIdx.x; idx < 8 * Dd; idx += TPB) {
    int r = idx >> 8, d = idx & 255;
    m0s[r][d] = md0T[(size_t)(i0 + r) * Dd + d];
  }
  __syncthreads();
  float acc[8] = {0.f, 0.f, 0.f, 0.f, 0.f, 0.f, 0.f, 0.f};
  for (int d = 0; d < Dd; ++d) {
    float mv = md1[(size_t)d * Nn + j];
#pragma unroll
    for (int r = 0; r < 8; ++r) acc[r] += m0s[r][d] * mv;
  }
  float vr[8];
#pragma unroll
  for (int r = 0; r < 8; ++r) {
    vr[r] = expf(acc[r] * 0.0625f);
    K[(size_t)(i0 + r) * LDKc + j] = vr[r];
  }
  *(float4*)&KT[(size_t)j * LDKc + i0]     = make_float4(vr[0], vr[1], vr[2], vr[3]);
  *(float4*)&KT[(size_t)j * LDKc + i0 + 4] = make_float4(vr[4], vr[5], vr[6], vr[7]);
}

// split launches (path A)
__global__ __launch_bounds__(TPB) void k_h(const float* __restrict__ W1,
                                           const float* __restrict__ md0,
                                           const float* __restrict__ md1,
                                           float* __restrict__ hA,
                                           float* __restrict__ hBt) {
  h_body(blockIdx.x, blockIdx.y, blockIdx.z, W1, md0, md1, hA, hBt);
}
__global__ __launch_bounds__(TPB) void k_buildK(const float* __restrict__ md0T,
                                                const float* __restrict__ md1,
                                                float* __restrict__ K,
                                                float* __restrict__ KT) {
  buildK_body(blockIdx.x, blockIdx.y, md0T, md1, K, KT);
}
// merged h + buildK (path B): 1024 flat blocks; both depend only on mdesc.
__global__ __launch_bounds__(TPB) void k_hbk(const float* __restrict__ W1,
                                             const float* __restrict__ md0,
                                             const float* __restrict__ md1,
                                             const float* __restrict__ md0T,
                                             float* __restrict__ hA,
                                             float* __restrict__ hBt,
                                             float* __restrict__ K,
                                             float* __restrict__ KT) {
  int fb = blockIdx.x;
  if (fb < 512) {
    int z = fb >> 8, rem = fb & 255;
    h_body(rem & 3, rem >> 2, z, W1, md0, md1, hA, hBt);
  } else {
    int bb = fb - 512;
    buildK_body(bb & 3, bb >> 2, md0T, md1, K, KT);
  }
}

// attn[i,j] = b2 + sum_o W2[o]*relu(hA[i,o]+hBt[o,j]+b1[o]). grid (4,256)
__global__ __launch_bounds__(TPB) void k_attn(const float* __restrict__ hA,
                                              const float* __restrict__ hBt,
                                              const float* __restrict__ W2,
                                              const float* __restrict__ b1,
                                              const float* __restrict__ b2,
                                              float* __restrict__ attn) {
  int j = blockIdx.x * TPB + threadIdx.x;
  int i0 = blockIdx.y * 4;
  float bias = b2[0];
  float acc[4] = {bias, bias, bias, bias};
  for (int o = 0; o < 64; ++o) {
    float hb = hBt[(size_t)o * Nn + j] + b1[o];
    float w = W2[o];
#pragma unroll
    for (int r = 0; r < 4; ++r) {
      float t = hA[(size_t)(i0 + r) * 64 + o] + hb;
      acc[r] += w * fmaxf(t, 0.f);
    }
  }
#pragma unroll
  for (int r = 0; r < 4; ++r) attn[(size_t)(i0 + r) * Nn + j] = acc[r];
}

// merged: row stats (0..1023) + column partial stats (1024..1087) + W transposes
// (1088..1407) + sync-buffer resets (1408..1411). grid 1412
__global__ __launch_bounds__(TPB) void k_stats(const float* __restrict__ attn,
                                               float* __restrict__ rowM,
                                               float* __restrict__ rowS,
                                               float* __restrict__ cmp,
                                               float* __restrict__ csp,
                                               const float* __restrict__ Wz1,
                                               const float* __restrict__ Wz2,
                                               float* __restrict__ Wz1T,
                                               float* __restrict__ Wz2T,
                                               float* __restrict__ av,
                                               float* __restrict__ bv,
                                               float* __restrict__ rinvb,
                                               int* __restrict__ idx0,
                                               float* __restrict__ max0,
                                               int* __restrict__ idx1) {
  int t = threadIdx.x;
  if (blockIdx.x < 1024) {
    int i = blockIdx.x;
    const float* row = attn + (size_t)i * Nn;
    float m = -INFINITY;
    for (int q = 0; q < 4; ++q) m = fmaxf(m, row[t + q * TPB]);
    __shared__ float red[TPB];
    red[t] = m; __syncthreads();
    for (int s = TPB / 2; s > 0; s >>= 1) {
      if (t < s) red[t] = fmaxf(red[t], red[t + s]);
      __syncthreads();
    }
    m = red[0]; __syncthreads();
    float ssum = 0.f;
    for (int q = 0; q < 4; ++q) ssum += expf(row[t + q * TPB] - m);
    red[t] = ssum; __syncthreads();
    for (int s = TPB / 2; s > 0; s >>= 1) {
      if (t < s) red[t] += red[t + s];
      __syncthreads();
    }
    if (t == 0) { rowM[i] = m; rowS[i] = red[0]; }
  } else if (blockIdx.x < 1088) {
    int flat = blockIdx.x - 1024;     // 0..63
    int jx = flat & 3, c = flat >> 2;
    int j = jx * TPB + t, i0 = c * 64;
    float m = -INFINITY;
    for (int q = 0; q < 64; ++q) m = fmaxf(m, attn[(size_t)(i0 + q) * Nn + j]);
    float s = 0.f;
    for (int q = 0; q < 64; ++q) s += expf(attn[(size_t)(i0 + q) * Nn + j] - m);
    cmp[(size_t)c * Nn + j] = m;
    csp[(size_t)c * Nn + j] = s;
  } else if (blockIdx.x < 1408) {
    int b = blockIdx.x - 1088;        // 0..319
    if (b < 256) Wz1T[(size_t)t * 256 + b] = Wz1[(size_t)b * 256 + t];
    else {
      int o = b - 256;
      Wz2T[(size_t)t * 64 + o] = Wz2[(size_t)o * 256 + t];
    }
  } else {
    int idx = (blockIdx.x - 1408) * TPB + t;   // 0..1023
    av[idx] = 0.0f; bv[idx] = 0.0f; rinvb[idx] = -1.0f;
    idx0[idx] = -1; idx1[idx] = -1; max0[idx] = -1.0f;
    if (idx == 0) { av[1024] = 0.0f; bv[1024] = 0.0f; rinvb[1024] = -1.0f; }
  }
}

// zfeat partials with on-the-fly prob + inline colcomb (side 1). 8 rows/block.
// grid (128, 2, 2). P tile in LDS.
__global__ __launch_bounds__(TPB) void k_zfeat_part(const float* __restrict__ attn,
                                                    const float* __restrict__ rowM,
                                                    const float* __restrict__ rowS,
                                                    const float* __restrict__ cmp,
                                                    const float* __restrict__ csp,
                                                    const float* __restrict__ md0T,
                                                    const float* __restrict__ md1T,
                                                    float* __restrict__ part) {
  int d = threadIdx.x;
  int r0 = blockIdx.x * 8;
  int jc = blockIdx.y;
  int side = blockIdx.z;
  int j0 = jc * 512;
  __shared__ float P[8][512];
  __shared__ float colMs[8], colSs[8];
  if (side == 1 && threadIdx.x < 8) {
    int j = r0 + threadIdx.x;
    float m = -INFINITY;
    for (int c = 0; c < 16; ++c) m = fmaxf(m, cmp[(size_t)c * Nn + j]);
    float s = 0.f;
    for (int c = 0; c < 16; ++c) s += csp[(size_t)c * Nn + j] * expf(cmp[(size_t)c * Nn + j] - m);
    colMs[threadIdx.x] = m; colSs[threadIdx.x] = s;
  }
  __syncthreads();
  if (side == 0) {
    for (int idx = threadIdx.x; idx < 8 * 512; idx += TPB) {
      int r = idx >> 9, jj = idx & 511;
      int i = r0 + r;
      P[r][jj] = expf(attn[(size_t)i * Nn + j0 + jj] - rowM[i]) / rowS[i];
    }
  } else {
    for (int idx = threadIdx.x; idx < 8 * 512; idx += TPB) {
      int r = idx & 7, ii = idx >> 3;
      P[r][ii] = expf(attn[(size_t)(j0 + ii) * Nn + (r0 + r)] - colMs[r]) / colSs[r];
    }
  }
  __syncthreads();
  const float* mdT = side ? md0T : md1T;
  float acc[8] = {0.f, 0.f, 0.f, 0.f, 0.f, 0.f, 0.f, 0.f};
  for (int jj = 0; jj < 512; ++jj) {
    float mv = mdT[(size_t)(j0 + jj) * Dd + d];
#pragma unroll
    for (int r = 0; r < 8; ++r) acc[r] += P[r][jj] * mv;
  }
  float* dst = part + (size_t)(side * 2 + jc) * ((size_t)Nn * Dd);
#pragma unroll
  for (int r = 0; r < 8; ++r) dst[(size_t)(r0 + r) * Dd + d] = acc[r];
}

// zmlp, 8 rows per block; partial-sum fused on load. grid (128, 2)
__global__ __launch_bounds__(TPB) void k_zmlp(const float* __restrict__ part,
                                              const float* __restrict__ Wz1T,
                                              const float* __restrict__ bz1,
                                              const float* __restrict__ Wz2T,
                                              const float* __restrict__ bz2,
                                              const float* __restrict__ Wz3,
                                              const float* __restrict__ bz3,
                                              float* __restrict__ zA,
                                              float* __restrict__ zB) {
  int i0 = blockIdx.x * 8;
  int which = blockIdx.y;
  int t = threadIdx.x;
  __shared__ float xs[8][Dd];
  __shared__ float h1[8][Dd];
  __shared__ float h2[8][64];
  const float* p0 = part + (size_t)(which * 2) * ((size_t)Nn * Dd);
  const float* p1 = p0 + (size_t)Nn * Dd;
  for (int idx = t; idx < 8 * Dd; idx += TPB) {
    int r = idx >> 8, d = idx & 255;
    size_t off = (size_t)(i0 + r) * Dd + d;
    xs[r][d] = p0[off] + p1[off];
  }
  __syncthreads();
  float a1[8];
  float bb = bz1[t];
#pragma unroll
  for (int r = 0; r < 8; ++r) a1[r] = bb;
  for (int k = 0; k < Dd; ++k) {
    float w = Wz1T[(size_t)k * Dd + t];
#pragma unroll
    for (int r = 0; r < 8; ++r) a1[r] += w * xs[r][k];
  }
#pragma unroll
  for (int r = 0; r < 8; ++r) h1[r][t] = fmaxf(a1[r], 0.f);
  __syncthreads();
  {
    int o = t & 63, rg = (t >> 6) * 2;
    float b2v = bz2[o];
    float a20 = b2v, a21 = b2v;
    for (int k = 0; k < Dd; ++k) {
      float w = Wz2T[(size_t)k * 64 + o];
      a20 += w * h1[rg][k];
      a21 += w * h1[rg + 1][k];
    }
    h2[rg][o] = fmaxf(a20, 0.f);
    h2[rg + 1][o] = fmaxf(a21, 0.f);
  }
  __syncthreads();
  int wv = t >> 6, l = t & 63;
  float* z = which ? zB : zA;
#pragma unroll
  for (int s = 0; s < 2; ++s) {
    int r = wv * 2 + s;
    float p = Wz3[l] * h2[r][l];
#pragma unroll
    for (int off = 32; off > 0; off >>= 1) p += __shfl_down(p, off);
    if (l == 0) z[i0 + r] = p + bz3[0];
  }
}

// Dataflow Sinkhorn + fused epilogue + early exit. grid NB x PT. [r10 version]
__global__ __launch_bounds__(PT) void k_sink_flow2(
    const float* __restrict__ K, const float* __restrict__ KT,
    const float* __restrict__ zA, const float* __restrict__ zB,
    float* __restrict__ av, float* __restrict__ bv, float* __restrict__ rinvb,
    int* __restrict__ idx0, float* __restrict__ max0, int* __restrict__ idx1,
    float* __restrict__ out) {
  const int bid = blockIdx.x;
  const int t = threadIdx.x;
  const int w = t >> 6, l = t & 63;
  const int row = bid * 16 + w;
  const bool extra = (bid == 0 && w == 0);
  const float MU = 1.0f / 2048.0f;
  const float TOL = 1e-5f;
  const float E1 = 2.7182818284590452f;  // exp(alpha=1)

  const float* kp = K  + (size_t)row * LDKc;
  const float* tp = KT + (size_t)row * LDKc;
  float kr[16], tr[16];
#pragma unroll
  for (int q = 0; q < 16; ++q) { kr[q] = kp[l + 64 * q]; tr[q] = tp[l + 64 * q]; }
  const float k16 = (l == 0) ? expf(zA[row]) : 0.0f;   // K[row][1024]
  const float t16 = (l == 0) ? expf(zB[row]) : 0.0f;   // KT[row][1024]
  float k2[16], t2[16];
  float k216 = 0.0f, t216 = 0.0f;
#pragma unroll
  for (int q = 0; q < 16; ++q) { k2[q] = 0.0f; t2[q] = 0.0f; }
  if (extra) {
#pragma unroll
    for (int q = 0; q < 16; ++q) {
      k2[q] = expf(zB[l + 64 * q]);   // K[1024][j]
      t2[q] = expf(zA[l + 64 * q]);   // KT[1024][i]
    }
    if (l == 0) { k216 = E1; t216 = E1; }
  }

  __shared__ float xsA[LDKc];
  __shared__ float xsB[LDKc];
  __shared__ float rsv[LDKc];
  __shared__ int   i0s[Nn], i1s[Nn], v0s[Nn];
  __shared__ float msg[Nn];
  __shared__ int   chgflag;

  float prevB = -1.0f, prevB1024 = -1.0f;

  // ---- a gen0 = mu / (K · 1) ----
  {
    float acc = k16;
#pragma unroll
    for (int q = 0; q < 16; ++q) acc += kr[q];
#pragma unroll
    for (int off = 32; off > 0; off >>= 1) acc += __shfl_xor(acc, off);
    if (l == 0) astoref(&av[row], MU / acc);
    if (extra) {
      float a2 = k216;
#pragma unroll
      for (int q = 0; q < 16; ++q) a2 += k2[q];
#pragma unroll
      for (int off = 32; off > 0; off >>= 1) a2 += __shfl_xor(a2, off);
      if (l == 0) astoref(&av[1024], 0.5f / a2);
    }
  }

  for (int it = 0; it < SINK_ITERS; ++it) {
    const int sg = it & 1;
    xsA[t] = fabsf(pollsgn(&av[t], sg));
    if (t == 0) xsA[1024] = fabsf(pollsgn(&av[1024], sg));
    __syncthreads();                        // S1
    if (t == 0) chgflag = 0;
    // b gen it = nu / (KT a)
    {
      float acc = t16 * xsA[1024];
#pragma unroll
      for (int q = 0; q < 16; ++q) acc += tr[q] * xsA[l + 64 * q];
#pragma unroll
      for (int off = 32; off > 0; off >>= 1) acc += __shfl_xor(acc, off);
      if (l == 0) { float r = MU / acc; astoref(&bv[row], sg ? -r : r); }
      if (extra) {
        float a2 = t216 * xsA[1024];
#pragma unroll
        for (int q = 0; q < 16; ++q) a2 += t2[q] * xsA[l + 64 * q];
#pragma unroll
        for (int off = 32; off > 0; off >>= 1) a2 += __shfl_xor(a2, off);
        if (l == 0) { float r = 0.5f / a2; astoref(&bv[1024], sg ? -r : r); }
      }
    }
    // stage |b| + convergence test vs previous iteration
    {
      float nb = fabsf(pollsgn(&bv[t], sg));
      xsB[t] = nb;
      bool ch = fabsf(nb - prevB) > TOL * nb;
      prevB = nb;
      if (t == 0) {
        float nb2 = fabsf(pollsgn(&bv[1024], sg));
        xsB[1024] = nb2;
        ch |= fabsf(nb2 - prevB1024) > TOL * nb2;
        prevB1024 = nb2;
      }
      if (ch) chgflag = 1;                  // benign same-value race
    }
    __syncthreads();                        // S2
    if (chgflag == 0) break;                // identical data everywhere -> uniform break
    // a gen it+1 = mu / (K b)
    if (it + 1 < SINK_ITERS) {
      const int sn = (it + 1) & 1;
      float acc = k16 * xsB[1024];
#pragma unroll
      for (int q = 0; q < 16; ++q) acc += kr[q] * xsB[l + 64 * q];
#pragma unroll
      for (int off = 32; off > 0; off >>= 1) acc += __shfl_xor(acc, off);
      if (l == 0) { float r = MU / acc; astoref(&av[row], sn ? -r : r); }
      if (extra) {
        float a2 = k216 * xsB[1024];
#pragma unroll
        for (int q = 0; q < 16; ++q) a2 += k2[q] * xsB[l + 64 * q];
#pragma unroll
        for (int off = 32; off > 0; off >>= 1) a2 += __shfl_xor(a2, off);
        if (l == 0) { float r = 0.5f / a2; astoref(&av[1024], sn ? -r : r); }
      }
    }
  }

  // ---- rinv = 1/(K·b) ----
  {
    float acc = k16 * xsB[1024];
#pragma unroll
    for (int q = 0; q < 16; ++q) acc += kr[q] * xsB[l + 64 * q];
#pragma unroll
    for (int off = 32; off > 0; off >>= 1) acc += __shfl_xor(acc, off);
    if (l == 0) astoref(&rinvb[row], 1.0f / acc);
    if (extra) {
      float a2 = k216 * xsB[1024];
#pragma unroll
      for (int q = 0; q < 16; ++q) a2 += k2[q] * xsB[l + 64 * q];
#pragma unroll
      for (int off = 32; off > 0; off >>= 1) a2 += __shfl_xor(a2, off);
      if (l == 0) astoref(&rinvb[1024], 1.0f / a2);
    }
  }
  rsv[t] = pollp(&rinvb[t]);
  if (t == 0) rsv[1024] = pollp(&rinvb[1024]);
  __syncthreads();

  // ---- S rows + row argmax + col argmax ----
  float* Sbase = out + 4096;
  {
    float ri = rsv[row];
    float* srow = Sbase + (size_t)row * Mm;
    float bm = -1.0f; int bj = 0;
#pragma unroll
    for (int q = 0; q < 16; ++q) {
      int j = l + 64 * q;
      float s = (kr[q] * xsB[j]) * ri;
      srow[j] = s;
      if (s > bm) { bm = s; bj = j; }
    }
    if (l == 0) srow[1024] = (k16 * xsB[1024]) * ri;
#pragma unroll
    for (int off = 32; off > 0; off >>= 1) {
      float om = __shfl_xor(bm, off);
      int oj = __shfl_xor(bj, off);
      if (om > bm || (om == bm && oj < bj)) { bm = om; bj = oj; }
    }
    if (l == 0) { astorei(&idx0[row], bj); astoref(&max0[row], bm); }
    float bc = xsB[row];
    float cm = -1.0f; int ci = 0;
#pragma unroll
    for (int q = 0; q < 16; ++q) {
      int i = l + 64 * q;
      float v = (tr[q] * bc) * rsv[i];
      if (v > cm) { cm = v; ci = i; }
    }
#pragma unroll
    for (int off = 32; off > 0; off >>= 1) {
      float om = __shfl_xor(cm, off);
      int oi = __shfl_xor(ci, off);
      if (om > cm || (om == cm && oi < ci)) { cm = om; ci = oi; }
    }
    if (l == 0) astorei(&idx1[row], ci);
    if (extra) {  // S row 1024
      float ri2 = rsv[1024];
      float* sr2 = Sbase + (size_t)Nn * Mm;
#pragma unroll
      for (int q = 0; q < 16; ++q) {
        int j = l + 64 * q;
        sr2[j] = (k2[q] * xsB[j]) * ri2;
      }
      if (l == 0) sr2[1024] = (k216 * xsB[1024]) * ri2;
    }
  }

  // ---- mutual matching (block 0) ----
  if (bid == 0) {
    int j0  = polli(&idx0[t]);
    int i1v = polli(&idx1[t]);
    float mr = pollp(&max0[t]);
    i0s[t] = j0; i1s[t] = i1v;
    __syncthreads();
    bool mut0 = (i1s[j0] == t);
    float m0 = mut0 ? expf(mr) : 0.0f;
    bool val0 = mut0 && (m0 > 0.2f);
    msg[t] = m0; v0s[t] = val0 ? 1 : 0;
    out[t] = val0 ? (float)j0 : -1.0f;   // indices0
    out[2048 + t] = m0;                   // mscores0
    __syncthreads();
    bool mut1 = (i0s[i1v] == t);
    float m1 = mut1 ? msg[i1v] : 0.0f;
    bool val1 = mut1 && (v0s[i1v] != 0);
    out[1024 + t] = val1 ? (float)i1v : -1.0f;  // indices1
    out[3072 + t] = m1;                          // mscores1
  }
}

extern "C" void kernel_launch(void* const* d_in, const int* in_sizes, int n_in,
                              void* d_out, int out_size, void* d_ws, size_t ws_size,
                              hipStream_t stream) {
  (void)in_sizes; (void)n_in; (void)out_size;
  const float* desc0 = (const float*)d_in[0];
  const float* desc1 = (const float*)d_in[1];
  const float* Wp    = (const float*)d_in[2];
  const float* bp    = (const float*)d_in[3];
  const float* W1    = (const float*)d_in[4];
  const float* b1    = (const float*)d_in[5];
  const float* W2    = (const float*)d_in[6];
  const float* b2    = (const float*)d_in[7];
  const float* Wz1   = (const float*)d_in[8];
  const float* bz1   = (const float*)d_in[9];
  const float* Wz2   = (const float*)d_in[10];
  const float* bz2   = (const float*)d_in[11];
  const float* Wz3   = (const float*)d_in[12];
  const float* bz3   = (const float*)d_in[13];
  float* ws  = (float*)d_ws;
  float* out = (float*)d_out;
  dim3 blk(TPB);

  const bool pathB = ws_size >= NEED_B_FLOATS * sizeof(float);
  float* Kp  = ws + (pathB ? OF_K_B : OF_K_A);
  float* KTp = Kp + (size_t)Mm * LDKc;

  k_mdesc<<<dim3(4, 64, 2), blk, 0, stream>>>(Wp, bp, desc0, desc1,
                                              ws + OF_MD0, ws + OF_MD0T,
                                              ws + OF_MD1, ws + OF_MD1T);
  if (pathB) {
    // h and buildK both depend only on mdesc -> one merged launch (K in own region)
    k_hbk<<<dim3(1024), blk, 0, stream>>>(W1, ws + OF_MD0, ws + OF_MD1, ws + OF_MD0T,
                                          ws + OF_HA, ws + OF_HBT, Kp, KTp);
  } else {
    k_h<<<dim3(4, 64, 2), blk, 0, stream>>>(W1, ws + OF_MD0, ws + OF_MD1,
                                            ws + OF_HA, ws + OF_HBT);
  }
  k_attn<<<dim3(4, 256), blk, 0, stream>>>(ws + OF_HA, ws + OF_HBT, W2, b1, b2,
                                           ws + OF_ATTN);
  k_stats<<<dim3(1412), blk, 0, stream>>>(ws + OF_ATTN, ws + OF_ROWM, ws + OF_ROWS,
                                          ws + OF_CMP, ws + OF_CSP,
                                          Wz1, Wz2, ws + OF_WZ1T, ws + OF_WZ2T,
                                          ws + OF_AV, ws + OF_BV, ws + OF_RINV,
                                          (int*)(ws + OF_IDX0), ws + OF_MAX0,
                                          (int*)(ws + OF_IDX1));
  k_zfeat_part<<<dim3(128, 2, 2), blk, 0, stream>>>(ws + OF_ATTN,
                                                    ws + OF_ROWM, ws + OF_ROWS,
                                                    ws + OF_CMP, ws + OF_CSP,
                                                    ws + OF_MD0T, ws + OF_MD1T,
                                                    ws + OF_PART);
  k_zmlp<<<dim3(128, 2), blk, 0, stream>>>(ws + OF_PART, ws + OF_WZ1T, bz1,
                                           ws + OF_WZ2T, bz2, Wz3, bz3,
                                           ws + OF_ZA, ws + OF_ZB);
  if (!pathB) {
    // buildK last: clobbers attn/part region (both dead by now) in layout A
    k_buildK<<<dim3(4, 128), blk, 0, stream>>>(ws + OF_MD0T, ws + OF_MD1, Kp, KTp);
  }
  k_sink_flow2<<<dim3(NB), dim3(PT), 0, stream>>>(
      Kp, KTp, ws + OF_ZA, ws + OF_ZB,
      ws + OF_AV, ws + OF_BV, ws + OF_RINV,
      (int*)(ws + OF_IDX0), ws + OF_MAX0, (int*)(ws + OF_IDX1), out);
}